// Round 9
// baseline (861.670 us; speedup 1.0000x reference)
//
#include <hip/hip_runtime.h>

// GCN 2-layer. N=250000, E=4000000, 18 -> 16 -> 1.
// Bucket-binned edges (256 dst/bucket, NB=977), per-bucket segments sorted by
// src-slice (8 slices x 32K nodes = 2 MB of hs1). One persistent kernel
// (256 blocks, provably co-resident; hand-rolled grid barrier) walks slices
// in lockstep so every XCD L2 caches the same 2 MB hs1 window. R4/R6/R7 all
// pinned at ~45M gather-lines/s/CU (outstanding-miss x HBM/L3 latency wall);
// L2-hit latency is the remaining lever. R8's hipLaunchCooperativeKernel
// never launched (residency validation) -> own the barrier instead.
//
// out[d] = dis[d] * (sum_{s->d} hs[s] + hs[d]) + bias, hs pre-scaled by dis.

#define NB_BITS 8
#define BN (1 << NB_BITS)       // 256 nodes per bucket
#define NBQ 1024                // scan/histogram width (>= NB=977)
#define BIN_TPB 512
#define BIN_CHUNK 8192
#define ASTRIDE 17              // LDS pad
#define MAXSEG 6144             // max edges/bucket for LDS sort (mean 4094, sd 64)
#define NSL 8                   // src slices: 32768 nodes = 2 MB of hs1
#define SL_SHIFT 23             // pv >> 23 == src >> 15
#define GRID 256                // persistent kernel blocks (1/CU)
#define AGG_TPB 512

// per-block LDS histogram of dst buckets -> global bcnt
__global__ void bhist_kernel(const int* __restrict__ dst, int* __restrict__ bcnt, int E, int NB_) {
    __shared__ int cnt[NBQ];
    int t = threadIdx.x;
    for (int i = t; i < NBQ; i += BIN_TPB) cnt[i] = 0;
    __syncthreads();
    int base = blockIdx.x * BIN_CHUNK;
    int end = min(base + BIN_CHUNK, E);
#pragma unroll 4
    for (int e = base + t; e < end; e += BIN_TPB)
        atomicAdd(&cnt[dst[e] >> NB_BITS], 1);
    __syncthreads();
    for (int i = t; i < NB_; i += BIN_TPB)
        if (cnt[i] > 0) atomicAdd(&bcnt[i], cnt[i]);
}

// exclusive scan of bcnt -> bstart, cursor (1024 threads)
__global__ void bscan_kernel(const int* __restrict__ bcnt, int* __restrict__ bstart,
                             int* __restrict__ cursor, int NB_) {
    __shared__ int s[NBQ];
    int t = threadIdx.x;
    int v = (t < NB_) ? bcnt[t] : 0;
    s[t] = v;
    __syncthreads();
    for (int off = 1; off < NBQ; off <<= 1) {
        int add = (t >= off) ? s[t - off] : 0;
        __syncthreads();
        s[t] += add;
        __syncthreads();
    }
    int excl = s[t] - v;
    if (t < NB_) {
        bstart[t] = excl;
        cursor[t] = excl;
        if (t == NB_ - 1) bstart[NB_] = excl + v;
    }
}

// place edges: block reserves private contiguous range per bucket, writes
// packed (src<<8 | dst&255) via LDS cursors. All lines single-block-owned.
__global__ void bplace_kernel(const int* __restrict__ src, const int* __restrict__ dst,
                              int* __restrict__ cursor, int* __restrict__ pairs, int E, int NB_) {
    __shared__ int cnt[NBQ];
    __shared__ int lofs[NBQ];
    int t = threadIdx.x;
    for (int i = t; i < NBQ; i += BIN_TPB) cnt[i] = 0;
    __syncthreads();
    int base = blockIdx.x * BIN_CHUNK;
    int end = min(base + BIN_CHUNK, E);
#pragma unroll 4
    for (int e = base + t; e < end; e += BIN_TPB)
        atomicAdd(&cnt[dst[e] >> NB_BITS], 1);
    __syncthreads();
    for (int i = t; i < NB_; i += BIN_TPB)
        if (cnt[i] > 0) lofs[i] = atomicAdd(&cursor[i], cnt[i]);
    __syncthreads();
#pragma unroll 4
    for (int e = base + t; e < end; e += BIN_TPB) {
        int d = dst[e];
        int sv = src[e];
        int b = d >> NB_BITS;
        int p = atomicAdd(&lofs[b], 1);
        pairs[p] = (sv << NB_BITS) | (d & (BN - 1));
    }
}

// per-bucket: counting-sort segment by src slice (write back sorted + slice
// offsets) and compute deg -> dis. One block per bucket.
__global__ __launch_bounds__(256) void sortseg_kernel(int* __restrict__ pairs,
        const int* __restrict__ bstart, int* __restrict__ bslice,
        float* __restrict__ dis, int N) {
    __shared__ int bufA[MAXSEG];
    __shared__ int bufB[MAXSEG];
    __shared__ int scnt[NSL];
    __shared__ int sofs[NSL + 1];
    __shared__ int dcnt[BN];
    int b = blockIdx.x, t = threadIdx.x;
    int s0 = bstart[b], s1 = bstart[b + 1];
    int seg = s1 - s0;
    for (int i = t; i < BN; i += 256) dcnt[i] = 0;
    if (t < NSL) scnt[t] = 0;
    __syncthreads();
    if (seg <= MAXSEG) {
        for (int i = t; i < seg; i += 256) {
            int pv = pairs[s0 + i];
            bufA[i] = pv;
            atomicAdd(&scnt[pv >> SL_SHIFT], 1);
            atomicAdd(&dcnt[pv & (BN - 1)], 1);
        }
        __syncthreads();
        if (t == 0) {
            int run = 0;
#pragma unroll
            for (int s = 0; s < NSL; s++) { sofs[s] = run; run += scnt[s]; }
            sofs[NSL] = run;
        }
        __syncthreads();
        if (t <= NSL) bslice[b * (NSL + 1) + t] = s0 + sofs[t];
        if (t < NSL) scnt[t] = sofs[t];   // cursors
        __syncthreads();
        for (int i = t; i < seg; i += 256) {
            int pv = bufA[i];
            int p = atomicAdd(&scnt[pv >> SL_SHIFT], 1);
            bufB[p] = pv;
        }
        __syncthreads();
        for (int i = t; i < seg; i += 256) pairs[s0 + i] = bufB[i];
    } else {
        // fallback (should never trigger): unsorted, all edges in phase 0
        for (int i = t; i < seg; i += 256)
            atomicAdd(&dcnt[pairs[s0 + i] & (BN - 1)], 1);
        if (t <= NSL) bslice[b * (NSL + 1) + t] = (t == 0) ? s0 : s1;
        __syncthreads();
    }
    int nbase = b << NB_BITS;
    for (int i = t; i < BN; i += 256) {
        int n = nbase + i;
        if (n < N) dis[n] = rsqrtf((float)dcnt[i] + 1.0f);
    }
}

// hs1[n,f] = (x[n] @ W1)[f] * dis[n]
__global__ void h1_kernel(const float* __restrict__ x, const float* __restrict__ W1,
                          const float* __restrict__ dis, float* __restrict__ hs1, int N) {
    __shared__ float w[18 * 16];
    for (int i = threadIdx.x; i < 18 * 16; i += blockDim.x) w[i] = W1[i];
    __syncthreads();
    int n = blockIdx.x * blockDim.x + threadIdx.x;
    if (n >= N) return;
    const float2* x2 = (const float2*)(x + (size_t)n * 18);
    float xv[18];
#pragma unroll
    for (int k = 0; k < 9; k++) {
        float2 v = x2[k];
        xv[2 * k] = v.x;
        xv[2 * k + 1] = v.y;
    }
    float d = dis[n];
    float acc[16];
#pragma unroll
    for (int f = 0; f < 16; f++) acc[f] = 0.0f;
#pragma unroll
    for (int k = 0; k < 18; k++) {
        float xk = xv[k];
#pragma unroll
        for (int f = 0; f < 16; f++) acc[f] = fmaf(xk, w[k * 16 + f], acc[f]);
    }
    float4* outp = (float4*)(hs1 + (size_t)n * 16);
#pragma unroll
    for (int q = 0; q < 4; q++) {
        float4 v;
        v.x = acc[q * 4 + 0] * d;
        v.y = acc[q * 4 + 1] * d;
        v.z = acc[q * 4 + 2] * d;
        v.w = acc[q * 4 + 3] * d;
        outp[q] = v;
    }
}

__device__ __forceinline__ void edge_accum(float* __restrict__ a, int dl,
                                           float4 v0, float4 v1, float4 v2, float4 v3) {
    float* p = a + dl * ASTRIDE;
    atomicAdd(p + 0, v0.x);  atomicAdd(p + 1, v0.y);
    atomicAdd(p + 2, v0.z);  atomicAdd(p + 3, v0.w);
    atomicAdd(p + 4, v1.x);  atomicAdd(p + 5, v1.y);
    atomicAdd(p + 6, v1.z);  atomicAdd(p + 7, v1.w);
    atomicAdd(p + 8, v2.x);  atomicAdd(p + 9, v2.y);
    atomicAdd(p + 10, v2.z); atomicAdd(p + 11, v2.w);
    atomicAdd(p + 12, v3.x); atomicAdd(p + 13, v3.y);
    atomicAdd(p + 14, v3.z); atomicAdd(p + 15, v3.w);
}

// sense-free grid barrier: bar[0]=arrival counter, bar[1]=generation.
// Generation-relative spin -> safe across graph replays (memset'd each launch).
__device__ __forceinline__ void grid_barrier(int* bar) {
    __syncthreads();
    if (threadIdx.x == 0) {
        __threadfence();
        int g0 = __hip_atomic_load(bar + 1, __ATOMIC_ACQUIRE, __HIP_MEMORY_SCOPE_AGENT);
        int old = __hip_atomic_fetch_add(bar, 1, __ATOMIC_ACQ_REL, __HIP_MEMORY_SCOPE_AGENT);
        if (old == GRID - 1) {
            __hip_atomic_store(bar, 0, __ATOMIC_RELAXED, __HIP_MEMORY_SCOPE_AGENT);
            __hip_atomic_fetch_add(bar + 1, 1, __ATOMIC_RELEASE, __HIP_MEMORY_SCOPE_AGENT);
        } else {
            while (__hip_atomic_load(bar + 1, __ATOMIC_ACQUIRE, __HIP_MEMORY_SCOPE_AGENT) == g0)
                __builtin_amdgcn_s_sleep(2);
        }
    }
    __syncthreads();
}

// persistent: layer-1 slice-phased gather+accumulate (4 buckets/block),
// epilogue -> hs2, barrier, layer-2 aggregate -> out.
__global__ __launch_bounds__(AGG_TPB, 4) void agg_all_kernel(
        const int* __restrict__ pairs, const int* __restrict__ bslice,
        const float* __restrict__ hs1, const float* __restrict__ dis,
        const float* __restrict__ b1, const float* __restrict__ W2,
        const float* __restrict__ b2, float* __restrict__ hs2,
        float* __restrict__ out, int* bar, int N, int NB_) {
    __shared__ float acc[4 * BN * ASTRIDE];  // 69632 B
    int g = blockIdx.x, t = threadIdx.x;
    for (int i = t; i < 4 * BN * ASTRIDE; i += AGG_TPB) acc[i] = 0.f;
    __syncthreads();
    // layer-1: 8 lockstep slice phases; all blocks gather from the same 2 MB window
    for (int s = 0; s < NSL; s++) {
        for (int k = 0; k < 4; k++) {
            int b = g + (k << 8);
            if (b >= NB_) break;           // uniform across block
            float* ab = acc + k * (BN * ASTRIDE);
            int fs = bslice[b * (NSL + 1) + s];
            int fe = bslice[b * (NSL + 1) + s + 1];
            int e = fs + t;
            for (; e + AGG_TPB < fe; e += 2 * AGG_TPB) {
                int pva = pairs[e];
                int pvb = pairs[e + AGG_TPB];
                const float4* ha = (const float4*)(hs1 + ((size_t)(pva >> NB_BITS) << 4));
                const float4* hb = (const float4*)(hs1 + ((size_t)(pvb >> NB_BITS) << 4));
                float4 a0 = ha[0], a1 = ha[1], a2 = ha[2], a3 = ha[3];
                float4 c0 = hb[0], c1 = hb[1], c2 = hb[2], c3 = hb[3];
                edge_accum(ab, pva & (BN - 1), a0, a1, a2, a3);
                edge_accum(ab, pvb & (BN - 1), c0, c1, c2, c3);
            }
            for (; e < fe; e += AGG_TPB) {
                int pv = pairs[e];
                const float4* hp = (const float4*)(hs1 + ((size_t)(pv >> NB_BITS) << 4));
                float4 v0 = hp[0], v1 = hp[1], v2 = hp[2], v3 = hp[3];
                edge_accum(ab, pv & (BN - 1), v0, v1, v2, v3);
            }
        }
        if (s < NSL - 1) grid_barrier(bar);
    }
    __syncthreads();
    // epilogue: relu + W2 dot + dis scale -> hs2
    int f = t & 15;
    float bbf = b1[f], wwf = W2[f];
    for (int k = 0; k < 4; k++) {
        int b = g + (k << 8);
        if (b >= NB_) break;
        float* ab = acc + k * (BN * ASTRIDE);
        int nbase = b << NB_BITS;
        for (int nl = t >> 4; nl < BN; nl += AGG_TPB / 16) {
            int n = nbase + nl;
            float d = 0.f, p = 0.f;
            if (n < N) {
                d = dis[n];
                float self = hs1[(size_t)n * 16 + f];
                p = fmaxf(d * (ab[nl * ASTRIDE + f] + self) + bbf, 0.f) * wwf;
            }
            p += __shfl_xor(p, 1);
            p += __shfl_xor(p, 2);
            p += __shfl_xor(p, 4);
            p += __shfl_xor(p, 8);
            if (f == 0 && n < N) hs2[n] = p * d;
        }
    }
    grid_barrier(bar);   // includes threadfence; hs2 visible device-wide
    // layer-2: aggregate hs2 (1 MB, L2-resident). Reuse acc as 4x BN floats.
    for (int i = t; i < 4 * BN; i += AGG_TPB) acc[i] = 0.f;
    __syncthreads();
    for (int k = 0; k < 4; k++) {
        int b = g + (k << 8);
        if (b >= NB_) break;
        float* a2 = acc + k * BN;
        int fs = bslice[b * (NSL + 1)];
        int fe = bslice[b * (NSL + 1) + NSL];
        int e = fs + t;
        for (; e + 3 * AGG_TPB < fe; e += 4 * AGG_TPB) {
            int pv0 = pairs[e];
            int pv1 = pairs[e + AGG_TPB];
            int pv2 = pairs[e + 2 * AGG_TPB];
            int pv3 = pairs[e + 3 * AGG_TPB];
            float v0 = hs2[pv0 >> NB_BITS];
            float v1 = hs2[pv1 >> NB_BITS];
            float v2 = hs2[pv2 >> NB_BITS];
            float v3 = hs2[pv3 >> NB_BITS];
            atomicAdd(&a2[pv0 & (BN - 1)], v0);
            atomicAdd(&a2[pv1 & (BN - 1)], v1);
            atomicAdd(&a2[pv2 & (BN - 1)], v2);
            atomicAdd(&a2[pv3 & (BN - 1)], v3);
        }
        for (; e < fe; e += AGG_TPB) {
            int pv = pairs[e];
            atomicAdd(&a2[pv & (BN - 1)], hs2[pv >> NB_BITS]);
        }
    }
    __syncthreads();
    for (int k = 0; k < 4; k++) {
        int b = g + (k << 8);
        if (b >= NB_) break;
        float* a2 = acc + k * BN;
        int nbase = b << NB_BITS;
        for (int i = t; i < BN; i += AGG_TPB) {
            int n = nbase + i;
            if (n < N) out[n] = dis[n] * (a2[i] + hs2[n]) + b2[0];
        }
    }
}

extern "C" void kernel_launch(void* const* d_in, const int* in_sizes, int n_in,
                              void* d_out, int out_size, void* d_ws, size_t ws_size,
                              hipStream_t stream) {
    const float* x = (const float*)d_in[0];
    const int* edge_index = (const int*)d_in[1];
    const float* W1 = (const float*)d_in[2];
    const float* b1 = (const float*)d_in[3];
    const float* W2 = (const float*)d_in[4];
    const float* b2 = (const float*)d_in[5];
    float* out = (float*)d_out;

    int N = in_sizes[0] / 18;
    const int E = in_sizes[1] / 2;
    const int* src = edge_index;
    const int* dst = edge_index + E;
    int NB = (N + BN - 1) / BN;  // 977

    // ws layout (4B words): pairs[E], hs1[16N], hs2[N], dis[N],
    // bstart[NB+1], cursor[NB], bcnt[NB], bar[2], bslice[NB*9]  ~= 34.1 MB
    int* ws = (int*)d_ws;
    int* pairs = ws;
    float* hs1 = (float*)(ws + (size_t)E);
    float* hs2 = hs1 + (size_t)16 * N;
    float* dis = hs2 + N;
    int* bstart = (int*)(dis + N);
    int* cursor = bstart + NB + 1;
    int* bcnt = cursor + NB;
    int* bar = bcnt + NB;
    int* bslice = bar + 2;

    // zero bcnt + barrier state (ws is re-poisoned 0xAA before every launch)
    hipMemsetAsync(bcnt, 0, (NB + 2) * sizeof(int), stream);

    int binBlocks = (E + BIN_CHUNK - 1) / BIN_CHUNK;  // 489
    int nBlocksN = (N + 255) / 256;

    bhist_kernel<<<binBlocks, BIN_TPB, 0, stream>>>(dst, bcnt, E, NB);
    bscan_kernel<<<1, NBQ, 0, stream>>>(bcnt, bstart, cursor, NB);
    bplace_kernel<<<binBlocks, BIN_TPB, 0, stream>>>(src, dst, cursor, pairs, E, NB);
    sortseg_kernel<<<NB, 256, 0, stream>>>(pairs, bstart, bslice, dis, N);
    h1_kernel<<<nBlocksN, 256, 0, stream>>>(x, W1, dis, hs1, N);
    agg_all_kernel<<<GRID, AGG_TPB, 0, stream>>>(pairs, bslice, hs1, dis, b1, W2,
                                                 b2, hs2, out, bar, N, NB);
}